// Round 5
// baseline (663.394 us; speedup 1.0000x reference)
//
#include <hip/hip_runtime.h>

// z = conv3x3(x, w) (pad 1, cross-correlation, NCHW/OIHW); LIF scan over t:
//   v = v + (z - v)*0.5 ; s = (v >= 1) ; v = s ? 0 : v
// NUMERICS INVARIANT (verified bit-exact R5/R6): per output element the conv
// is a SINGLE sequential f32 FMA chain over k = (tap, ci), tap = ky*3+kx
// outer, ci INNERMOST (Eigen/XLA-CPU order), acc starts at 0; padding taps are
// exact fma no-ops (zero halo). LIF ops separately rounded; *0.5 exact.
// R12: (a) LIF restructured to load-all-16 / scan-in-regs / store-all-16:
// 16 loads in flight per wave (was ~2) -> latency-bound scan becomes BW-bound.
// (b) conv cib unroll 2->4 for deeper xv/weight prefetch under FMA bursts.
// Established R11: bank-conflict count per ds_read_b128 is inherent (~8.9,
// layout-invariant) — no further swizzle attempts.

namespace {
constexpr int T = 16, N = 8, C = 64, H = 64, W = 64;
constexpr int HW   = H * W;       // 4096
constexpr int CHW  = C * HW;      // 262144
constexpr int NCHW = N * CHW;     // 2097152
constexpr int NWT  = C * C * 9;   // 36864
constexpr int NPOS = 10 * 18;     // 180 halo positions (8+2 rows, 16+2 cols)
}

// Transpose weights (O,I,3,3) -> wt2[tap][ci][cout]: per (tap,ci) couts are
// contiguous -> wave-uniform s_load of 16 floats per wave per (tap,ci).
__global__ void wtr_kernel(const float* __restrict__ w, float* __restrict__ wt2) {
    int i = blockIdx.x * 256 + threadIdx.x;     // i = (cout*64 + ci)*9 + tap
    if (i >= NWT) return;
    int tap  = i % 9;
    int rem  = i / 9;
    int ci   = rem % 64;
    int cout = rem / 64;
    wt2[(tap * 64 + ci) * 64 + cout] = w[i];
}

// Conv only. Block: 256 threads = 4 waves = one (t, n, 8x16 tile), 64 couts.
// Wave w: 64 lanes cover all 128 pixels (2 per lane: px, px+8); couts
// [16w, 16w+16). LDS float4-granule layout: granule = cib*NPOS + pos,
// pos = dy*18+dx; element (pos,ci) at float slot (ci>>2)*720 + pos*4 + (ci&3).
__global__ __launch_bounds__(256, 3) void conv_kernel(
    const float* __restrict__ x,
    const float* __restrict__ wt2,
    float*       __restrict__ zo)
{
#pragma clang fp contract(off)
    __shared__ float xs[16 * NPOS * 4];   // 16 ci-granules x 180 pos x 16B = 46.08KB

    const int tid  = threadIdx.x;
    const int wave = __builtin_amdgcn_readfirstlane(tid >> 6);
    const int lane = tid & 63;
    const int px = lane & 7;           // second pixel at px+8
    const int py = lane >> 3;
    const int c0 = wave << 4;          // 16 couts per wave

    const int bid  = blockIdx.x;       // 4096 = 16 t * 8 n * 32 tiles
    const int t    = bid >> 8;
    const int r    = bid & 255;
    const int n    = r >> 5;
    const int tile = r & 31;
    const int th0 = (tile >> 2) << 3;  // 8 row-tiles
    const int tw0 = (tile & 3) << 4;   // 4 col-tiles (16 wide)

    const float* xt = x + (size_t)(t * N + n) * CHW;

    // Stage x[t][n][ci][th0-1..+8][tw0-1..+16] transposed into LDS (zero halo).
#pragma unroll
    for (int it = 0; it < 45; ++it) {              // 11520 = 45 * 256
        int j  = tid + it * 256;
        int ci = j / NPOS;
        int rr = j - ci * NPOS;
        int dy = rr / 18;
        int dx = rr - dy * 18;
        int hh = th0 - 1 + dy;
        int ww = tw0 - 1 + dx;
        float val = 0.0f;
        if ((unsigned)hh < (unsigned)H && (unsigned)ww < (unsigned)W)
            val = xt[ci * HW + hh * W + ww];
        xs[(ci >> 2) * (NPOS * 4) + rr * 4 + (ci & 3)] = val;
    }
    __syncthreads();

    float acc0[16], acc1[16];
#pragma unroll
    for (int i = 0; i < 16; ++i) { acc0[i] = 0.0f; acc1[i] = 0.0f; }

    // Chain per acc[cc]: tap outer (9), ci 0..63 ascending inner; one fmaf
    // per k; only load scheduling varies, never FMA order. Both pixels'
    // chains are independent and identically ordered.
    for (int tap = 0; tap < 9; ++tap) {
        const int ky = tap / 3, kx = tap - 3 * ky;
        const int pos = (py + ky) * 18 + (px + kx);   // second pixel: pos + 8
        const float4* xp = (const float4*)xs + pos;   // + cib*NPOS granules
        const float* wtap = wt2 + tap * 4096 + c0;    // wave-uniform
#pragma unroll 4
        for (int cib = 0; cib < 16; ++cib) {
            const float4 xv0 = xp[cib * NPOS];
            const float4 xv1 = xp[cib * NPOS + 8];
            const float* wp = wtap + cib * 256;       // (tap, ci=4*cib) block
#pragma unroll
            for (int cc = 0; cc < 16; ++cc) {
                float w0 = wp[cc];
                acc0[cc] = fmaf(w0, xv0.x, acc0[cc]);
                acc1[cc] = fmaf(w0, xv1.x, acc1[cc]);
            }
#pragma unroll
            for (int cc = 0; cc < 16; ++cc) {
                float w1 = wp[64 + cc];
                acc0[cc] = fmaf(w1, xv0.y, acc0[cc]);
                acc1[cc] = fmaf(w1, xv1.y, acc1[cc]);
            }
#pragma unroll
            for (int cc = 0; cc < 16; ++cc) {
                float w2 = wp[128 + cc];
                acc0[cc] = fmaf(w2, xv0.z, acc0[cc]);
                acc1[cc] = fmaf(w2, xv1.z, acc1[cc]);
            }
#pragma unroll
            for (int cc = 0; cc < 16; ++cc) {
                float w3 = wp[192 + cc];
                acc0[cc] = fmaf(w3, xv0.w, acc0[cc]);
                acc1[cc] = fmaf(w3, xv1.w, acc1[cc]);
            }
        }
    }

    float* zt = zo + (size_t)(t * N + n) * CHW;
    const int pbase = (th0 + py) * W + (tw0 + px);
#pragma unroll
    for (int cc = 0; cc < 16; ++cc) {
        zt[(c0 + cc) * HW + pbase]     = acc0[cc];
        zt[(c0 + cc) * HW + pbase + 8] = acc1[cc];
    }
}

// LIF scan, in-place on zo (reads z, writes 0/1 spikes). One thread per float4
// neuron group. Phase 1: load all 16 t-slices (16 loads in flight). Phase 2:
// scan in registers. Phase 3: store all 16. Per-element op order unchanged
// (loads/stores don't round; each element owned by exactly one thread).
__global__ void lif_kernel(float* __restrict__ zo) {
#pragma clang fp contract(off)
    const int gid = blockIdx.x * 256 + threadIdx.x;   // [0, NCHW/4)
    float4 z[T];
#pragma unroll
    for (int t = 0; t < T; ++t)
        z[t] = *((const float4*)(zo + (size_t)t * NCHW) + gid);

    float4 v;
    v.x = 0.0f; v.y = 0.0f; v.z = 0.0f; v.w = 0.0f;
#pragma unroll
    for (int t = 0; t < T; ++t) {
        float4 zt = z[t];
        float4 s;
#define LIF_STEP(comp) { float d = zt.comp - v.comp; float hh = d * 0.5f;      \
        v.comp = v.comp + hh;                                                   \
        if (v.comp >= 1.0f) { s.comp = 1.0f; v.comp = 0.0f; }                   \
        else                { s.comp = 0.0f; } }
        LIF_STEP(x) LIF_STEP(y) LIF_STEP(z) LIF_STEP(w)
#undef LIF_STEP
        z[t] = s;
    }

#pragma unroll
    for (int t = 0; t < T; ++t)
        *((float4*)(zo + (size_t)t * NCHW) + gid) = z[t];
}

extern "C" void kernel_launch(void* const* d_in, const int* in_sizes, int n_in,
                              void* d_out, int out_size, void* d_ws, size_t ws_size,
                              hipStream_t stream) {
    const float* x = (const float*)d_in[0];
    const float* w = (const float*)d_in[1];
    if (n_in >= 2 && in_sizes[0] < in_sizes[1]) {   // defensive: pick by size
        const float* tmp = x; x = w; w = tmp;
    }
    float* out = (float*)d_out;
    float* wt2 = (float*)d_ws;                       // 36864 floats = 144 KB

    wtr_kernel<<<(NWT + 255) / 256, 256, 0, stream>>>(w, wt2);
    conv_kernel<<<T * N * 32, 256, 0, stream>>>(x, wt2, out);
    lif_kernel<<<NCHW / 1024, 256, 0, stream>>>(out);
}

// Round 6
// 632.158 us; speedup vs baseline: 1.0494x; 1.0494x over previous
//
#include <hip/hip_runtime.h>

// z = conv3x3(x, w) (pad 1, cross-correlation, NCHW/OIHW); LIF scan over t:
//   v = v + (z - v)*0.5 ; s = (v >= 1) ; v = s ? 0 : v
// NUMERICS INVARIANT (verified bit-exact R5/R6): per output element the conv
// is a SINGLE sequential f32 FMA chain over k = (tap, ci), tap = ky*3+kx
// outer, ci INNERMOST (Eigen/XLA-CPU order), acc starts at 0; padding taps are
// exact fma no-ops (zero halo). LIF ops separately rounded; *0.5 exact.
// R13: consolidation to best-measured components.
//  - conv = R11 exactly (2 px/lane 8x16 tile, cib unroll 2): 481 us proven.
//    (R12 showed unroll 4 regresses -35us; R10 showed occupancy >12 waves/CU
//    is not the lever; R7-R11 showed bank conflicts are inherent ~8.9/read.)
//  - lif = R10 simple float4 in-place (best remainder across 4 variants;
//    16 VGPR -> max occupancy). lif kernel itself ~55us vs 43us BW floor;
//    fixed harness overhead ~85-130us established via R9 subtraction.

namespace {
constexpr int T = 16, N = 8, C = 64, H = 64, W = 64;
constexpr int HW   = H * W;       // 4096
constexpr int CHW  = C * HW;      // 262144
constexpr int NCHW = N * CHW;     // 2097152
constexpr int NWT  = C * C * 9;   // 36864
constexpr int NPOS = 10 * 18;     // 180 halo positions (8+2 rows, 16+2 cols)
}

// Transpose weights (O,I,3,3) -> wt2[tap][ci][cout]: per (tap,ci) couts are
// contiguous -> wave-uniform s_load of 16 floats per wave per (tap,ci).
__global__ void wtr_kernel(const float* __restrict__ w, float* __restrict__ wt2) {
    int i = blockIdx.x * 256 + threadIdx.x;     // i = (cout*64 + ci)*9 + tap
    if (i >= NWT) return;
    int tap  = i % 9;
    int rem  = i / 9;
    int ci   = rem % 64;
    int cout = rem / 64;
    wt2[(tap * 64 + ci) * 64 + cout] = w[i];
}

// Conv only. Block: 256 threads = 4 waves = one (t, n, 8x16 tile), 64 couts.
// Wave w: 64 lanes cover all 128 pixels (2 per lane: px, px+8); couts
// [16w, 16w+16). LDS float4-granule layout: granule = cib*NPOS + pos,
// pos = dy*18+dx; element (pos,ci) at float slot (ci>>2)*720 + pos*4 + (ci&3).
__global__ __launch_bounds__(256, 3) void conv_kernel(
    const float* __restrict__ x,
    const float* __restrict__ wt2,
    float*       __restrict__ zo)
{
#pragma clang fp contract(off)
    __shared__ float xs[16 * NPOS * 4];   // 16 ci-granules x 180 pos x 16B = 46.08KB

    const int tid  = threadIdx.x;
    const int wave = __builtin_amdgcn_readfirstlane(tid >> 6);
    const int lane = tid & 63;
    const int px = lane & 7;           // second pixel at px+8
    const int py = lane >> 3;
    const int c0 = wave << 4;          // 16 couts per wave

    const int bid  = blockIdx.x;       // 4096 = 16 t * 8 n * 32 tiles
    const int t    = bid >> 8;
    const int r    = bid & 255;
    const int n    = r >> 5;
    const int tile = r & 31;
    const int th0 = (tile >> 2) << 3;  // 8 row-tiles
    const int tw0 = (tile & 3) << 4;   // 4 col-tiles (16 wide)

    const float* xt = x + (size_t)(t * N + n) * CHW;

    // Stage x[t][n][ci][th0-1..+8][tw0-1..+16] transposed into LDS (zero halo).
#pragma unroll
    for (int it = 0; it < 45; ++it) {              // 11520 = 45 * 256
        int j  = tid + it * 256;
        int ci = j / NPOS;
        int rr = j - ci * NPOS;
        int dy = rr / 18;
        int dx = rr - dy * 18;
        int hh = th0 - 1 + dy;
        int ww = tw0 - 1 + dx;
        float val = 0.0f;
        if ((unsigned)hh < (unsigned)H && (unsigned)ww < (unsigned)W)
            val = xt[ci * HW + hh * W + ww];
        xs[(ci >> 2) * (NPOS * 4) + rr * 4 + (ci & 3)] = val;
    }
    __syncthreads();

    float acc0[16], acc1[16];
#pragma unroll
    for (int i = 0; i < 16; ++i) { acc0[i] = 0.0f; acc1[i] = 0.0f; }

    // Chain per acc[cc]: tap outer (9), ci 0..63 ascending inner; one fmaf
    // per k; only load scheduling varies, never FMA order. Both pixels'
    // chains are independent and identically ordered.
    for (int tap = 0; tap < 9; ++tap) {
        const int ky = tap / 3, kx = tap - 3 * ky;
        const int pos = (py + ky) * 18 + (px + kx);   // second pixel: pos + 8
        const float4* xp = (const float4*)xs + pos;   // + cib*NPOS granules
        const float* wtap = wt2 + tap * 4096 + c0;    // wave-uniform
#pragma unroll 2
        for (int cib = 0; cib < 16; ++cib) {
            const float4 xv0 = xp[cib * NPOS];
            const float4 xv1 = xp[cib * NPOS + 8];
            const float* wp = wtap + cib * 256;       // (tap, ci=4*cib) block
#pragma unroll
            for (int cc = 0; cc < 16; ++cc) {
                float w0 = wp[cc];
                acc0[cc] = fmaf(w0, xv0.x, acc0[cc]);
                acc1[cc] = fmaf(w0, xv1.x, acc1[cc]);
            }
#pragma unroll
            for (int cc = 0; cc < 16; ++cc) {
                float w1 = wp[64 + cc];
                acc0[cc] = fmaf(w1, xv0.y, acc0[cc]);
                acc1[cc] = fmaf(w1, xv1.y, acc1[cc]);
            }
#pragma unroll
            for (int cc = 0; cc < 16; ++cc) {
                float w2 = wp[128 + cc];
                acc0[cc] = fmaf(w2, xv0.z, acc0[cc]);
                acc1[cc] = fmaf(w2, xv1.z, acc1[cc]);
            }
#pragma unroll
            for (int cc = 0; cc < 16; ++cc) {
                float w3 = wp[192 + cc];
                acc0[cc] = fmaf(w3, xv0.w, acc0[cc]);
                acc1[cc] = fmaf(w3, xv1.w, acc1[cc]);
            }
        }
    }

    float* zt = zo + (size_t)(t * N + n) * CHW;
    const int pbase = (th0 + py) * W + (tw0 + px);
#pragma unroll
    for (int cc = 0; cc < 16; ++cc) {
        zt[(c0 + cc) * HW + pbase]     = acc0[cc];
        zt[(c0 + cc) * HW + pbase + 8] = acc1[cc];
    }
}

// LIF scan, in-place on zo (reads z, writes 0/1 spikes). One thread per FOUR
// consecutive (n,c,h,w) neurons (float4); t-loop carries v in registers.
// Elementwise ops separately rounded, identical per-element order.
__global__ void lif_kernel(float* __restrict__ zo) {
#pragma clang fp contract(off)
    const int gid = blockIdx.x * 256 + threadIdx.x;   // [0, NCHW/4)
    float4 v;
    v.x = 0.0f; v.y = 0.0f; v.z = 0.0f; v.w = 0.0f;
#pragma unroll
    for (int t = 0; t < T; ++t) {
        float4* p = (float4*)(zo + (size_t)t * NCHW) + gid;
        float4 z = *p;
        float4 s;
#define LIF_STEP(comp) { float d = z.comp - v.comp; float hh = d * 0.5f;      \
        v.comp = v.comp + hh;                                                  \
        if (v.comp >= 1.0f) { s.comp = 1.0f; v.comp = 0.0f; }                  \
        else                { s.comp = 0.0f; } }
        LIF_STEP(x) LIF_STEP(y) LIF_STEP(z) LIF_STEP(w)
#undef LIF_STEP
        *p = s;
    }
}

extern "C" void kernel_launch(void* const* d_in, const int* in_sizes, int n_in,
                              void* d_out, int out_size, void* d_ws, size_t ws_size,
                              hipStream_t stream) {
    const float* x = (const float*)d_in[0];
    const float* w = (const float*)d_in[1];
    if (n_in >= 2 && in_sizes[0] < in_sizes[1]) {   // defensive: pick by size
        const float* tmp = x; x = w; w = tmp;
    }
    float* out = (float*)d_out;
    float* wt2 = (float*)d_ws;                       // 36864 floats = 144 KB

    wtr_kernel<<<(NWT + 255) / 256, 256, 0, stream>>>(w, wt2);
    conv_kernel<<<T * N * 32, 256, 0, stream>>>(x, wt2, out);
    lif_kernel<<<NCHW / 1024, 256, 0, stream>>>(out);
}